// Round 11
// baseline (333.965 us; speedup 1.0000x reference)
//
#include <hip/hip_runtime.h>
#include <hip/hip_bf16.h>
#include <math.h>

typedef unsigned short u16;
typedef __attribute__((ext_vector_type(8))) short bf16x8;
typedef __attribute__((ext_vector_type(8))) unsigned short u16x8;
typedef __attribute__((ext_vector_type(4))) float f32x4;
typedef __attribute__((ext_vector_type(16))) float f32x16;

__device__ __forceinline__ u16 f2b(float f) {
    unsigned x = __float_as_uint(f);
    x += 0x7fffu + ((x >> 16) & 1u);
    return (u16)(x >> 16);
}

__device__ __forceinline__ float b2f(short v) {
    return __uint_as_float(((unsigned)(u16)v) << 16);
}

__device__ __forceinline__ bf16x8 as_bf(uint4 v) {
    return __builtin_bit_cast(bf16x8, v);
}

// ---------------- transpose + fp32->bf16 convert ----------------
__global__ __launch_bounds__(256) void transpose_cvt(
    const float* __restrict__ in, u16* __restrict__ out,
    int R, int C, long long obs, int ocs)
{
    __shared__ float tile[64][65];
    int c0 = blockIdx.x * 64, r0 = blockIdx.y * 64;
    long long zb = (long long)blockIdx.z;
    const float* ip = in + zb * (long long)R * C;
    u16* op = out + zb * obs;
    int lane = threadIdx.x & 63, w = threadIdx.x >> 6;
#pragma unroll
    for (int i = 0; i < 16; i++) {
        int rr = w + (i << 2);
        tile[rr][lane] = ip[(long long)(r0 + rr) * C + c0 + lane];
    }
    __syncthreads();
#pragma unroll
    for (int i = 0; i < 16; i++) {
        int cc = w + (i << 2);
        op[(long long)(c0 + cc) * ocs + r0 + lane] = f2b(tile[lane][cc]);
    }
}

// ---------------- row layernorm -> bf16 ----------------
__global__ __launch_bounds__(256) void ln_kernel(
    const float* __restrict__ x, const float* __restrict__ w,
    const float* __restrict__ b, u16* __restrict__ out)
{
    int row = blockIdx.x;
    int tid = threadIdx.x;
    float4 v = ((const float4*)(x + (size_t)row * 1024))[tid];
    float s = v.x + v.y + v.z + v.w;
    float s2 = v.x * v.x + v.y * v.y + v.z * v.z + v.w * v.w;
#pragma unroll
    for (int o = 32; o > 0; o >>= 1) {
        s += __shfl_xor(s, o);
        s2 += __shfl_xor(s2, o);
    }
    __shared__ float red[8];
    int wv = tid >> 6;
    if ((tid & 63) == 0) { red[wv] = s; red[4 + wv] = s2; }
    __syncthreads();
    s = red[0] + red[1] + red[2] + red[3];
    s2 = red[4] + red[5] + red[6] + red[7];
    float mean = s * (1.0f / 1024.0f);
    float var = s2 * (1.0f / 1024.0f) - mean * mean;
    float inv = rsqrtf(var + 1e-12f);
    float4 wv4 = ((const float4*)w)[tid];
    float4 bv4 = ((const float4*)b)[tid];
    ushort4 o4;
    o4.x = f2b(wv4.x * (v.x - mean) * inv + bv4.x);
    o4.y = f2b(wv4.y * (v.y - mean) * inv + bv4.y);
    o4.z = f2b(wv4.z * (v.z - mean) * inv + bv4.z);
    o4.w = f2b(wv4.w * (v.w - mean) * inv + bv4.w);
    ((ushort4*)out)[(size_t)row * 256 + tid] = o4;
}

// ---------------- bf16 MFMA GEMM: C[M,N] = A[M,K] * Bt[N,K]^T + bias ----------------
// R11: T3 minimum 2-phase pipeline on the R10 structure — dbuf LDS (48 KB,
// 3 blocks/CU), STAGE(next) issued BEFORE compute(cur), ONE barrier per K-step.
// In-flight gload_lds overlap ds_read+MFMA; barrier drain lands after compute.
// T2 XOR-swizzle retained (R10: conflicts 9.4M -> 0): linear gload_lds dest +
// inverse-swizzled global source + swizzled read (rule #21).
// EPI 0: qkv scatter (q pre-scaled by log2e); 1: f32 out + resid; 2: gelu->bf16;
// 3: split-K atomicAdd into outf.
template<int EPI>
__global__ __launch_bounds__(256) void gemm_bt(
    const u16* __restrict__ A, const u16* __restrict__ Bt,
    const float* __restrict__ bias, int M, int N, int K, int Kc,
    float* __restrict__ outf, const float* __restrict__ resid,
    u16* __restrict__ outb,
    u16* __restrict__ qws, float* __restrict__ newk, float* __restrict__ newv,
    u16* __restrict__ Kt, u16* __restrict__ Vt)
{
    __shared__ u16 As[2][128][64];   // 32 KB
    __shared__ u16 Bs[2][64][64];    // 16 KB
    int tid = threadIdx.x;
    int gx = gridDim.x, gy = gridDim.y;
    int nwg = gx * gy * gridDim.z;
    int f = blockIdx.x + gx * (blockIdx.y + gy * blockIdx.z);
    int swz = (f & 7) * (nwg >> 3) + (f >> 3);
    int bx = swz % gx;
    int rest = swz / gx;
    int by = rest % gy;
    int chunk = rest / gy;
    int tn0 = bx * 64, tm0 = by * 128;
    int kbeg = chunk * Kc, kend = kbeg + Kc;

    int wave = tid >> 6, lane = tid & 63;
    int lrow = lane & 15, quad = lane >> 4;
    int srow = lane >> 3;                        // 0..7  == row&7 of the staged row
    int scolz = ((lane & 7) ^ srow) << 3;        // pre-swizzled source col (u16)

#define STAGE(k0, b)                                                                     \
    _Pragma("unroll")                                                                    \
    for (int i = 0; i < 4; i++) {                                                        \
        int r = wave * 32 + i * 8 + srow;                                                \
        __builtin_amdgcn_global_load_lds(                                                \
            (const __attribute__((address_space(1))) void*)(A + (size_t)(tm0 + r) * K + (k0) + scolz), \
            (__attribute__((address_space(3))) void*)(&As[b][0][0] + (wave * 4 + i) * 512), \
            16, 0, 0);                                                                   \
    }                                                                                    \
    _Pragma("unroll")                                                                    \
    for (int j = 0; j < 2; j++) {                                                        \
        int r = wave * 16 + j * 8 + srow;                                                \
        __builtin_amdgcn_global_load_lds(                                                \
            (const __attribute__((address_space(1))) void*)(Bt + (size_t)(tn0 + r) * K + (k0) + scolz), \
            (__attribute__((address_space(3))) void*)(&Bs[b][0][0] + (wave * 2 + j) * 512), \
            16, 0, 0);                                                                   \
    }

    f32x4 acc[2][4] = {};
    STAGE(kbeg, 0);
    __syncthreads();                 // prologue stage drained
    int buf = 0;
    for (int k0 = kbeg; k0 < kend; k0 += 64) {
        if (k0 + 64 < kend) { STAGE(k0 + 64, buf ^ 1); }   // in flight during compute
#pragma unroll
        for (int ks = 0; ks < 2; ks++) {
            bf16x8 af[2], bfg[4];
            int rsw = ((ks * 4 + quad) ^ (lrow & 7)) << 3;   // swizzled read col
#pragma unroll
            for (int mi = 0; mi < 2; mi++)
                af[mi] = *(const bf16x8*)(&As[buf][wave * 32 + mi * 16 + lrow][rsw]);
#pragma unroll
            for (int ni = 0; ni < 4; ni++)
                bfg[ni] = *(const bf16x8*)(&Bs[buf][ni * 16 + lrow][rsw]);
#pragma unroll
            for (int mi = 0; mi < 2; mi++)
#pragma unroll
                for (int ni = 0; ni < 4; ni++)
                    acc[mi][ni] = __builtin_amdgcn_mfma_f32_16x16x32_bf16(
                        af[mi], bfg[ni], acc[mi][ni], 0, 0, 0);
        }
        __syncthreads();             // drains stage(buf^1) + all reads of buf done
        buf ^= 1;
    }
#undef STAGE

#pragma unroll
    for (int mi = 0; mi < 2; mi++) {
#pragma unroll
        for (int ni = 0; ni < 4; ni++) {
#pragma unroll
            for (int r = 0; r < 4; r++) {
                int m = tm0 + wave * 32 + mi * 16 + quad * 4 + r;
                int n = tn0 + ni * 16 + lrow;
                float val = acc[mi][ni][r] +
                            ((EPI != 3 || chunk == 0) ? bias[n] : 0.0f);
                if (EPI == 0) {
                    int b = m >> 10, s = m & 1023;
                    int d = n & 63;
                    if (n < 1024) {
                        int h = n >> 6;
                        // pre-scale q by log2(e): attn uses exp2 directly
                        qws[(((size_t)b * 16 + h) * 1024 + s) * 64 + d] = f2b(val * 1.4426950408889634f);
                    } else if (n < 2048) {
                        int h = (n - 1024) >> 6;
                        newk[(((size_t)b * 16 + h) * 64 + d) * 1024 + s] = val;
                        Kt[(((size_t)b * 16 + h) * 2048 + 1024 + s) * 64 + d] = f2b(val);
                    } else {
                        int h = (n - 2048) >> 6;
                        newv[(((size_t)b * 16 + h) * 1024 + s) * 64 + d] = val;
                        Vt[(((size_t)b * 16 + h) * 64 + d) * 2048 + 1024 + s] = f2b(val);
                    }
                } else if (EPI == 1) {
                    size_t idx = (size_t)m * N + n;
                    outf[idx] = val + resid[idx];
                } else if (EPI == 2) {
                    float t = val + 0.044715f * val * val * val;
                    float gl = 0.5f * val * (1.0f + tanhf(0.7978845608028654f * t));
                    outb[(size_t)m * N + n] = f2b(gl);
                } else {
                    atomicAdd(outf + (size_t)m * N + n, val);
                }
            }
        }
    }
}

// ---------------- flash attention (R8 config, frozen) ----------------
__global__ __launch_bounds__(128, 2) void attn_kernel(
    const u16* __restrict__ q, const u16* __restrict__ Kt,
    const u16* __restrict__ Vt, u16* __restrict__ Opart,
    float* __restrict__ mlbuf)
{
    const int T = 2048;
    const float M2 = 28.853900817779268f;   // 20 * log2(e)
    __shared__ u16 Ks[2][64][64];
    __shared__ u16 Ps[2][32][72];
    int tid = threadIdx.x;
    int wg = blockIdx.x;                 // 0..1023
    int xcd = wg & 7, local = wg >> 3;   // head-clustered XCD swizzle (KV L2-resident)
    int bh = xcd * 4 + (local >> 5);
    int rem = local & 31;
    int chunk = rem >> 4;
    int s0 = (rem & 15) * 64;
    int tbeg = chunk << 10, tend = tbeg + 1024;
    int wave = tid >> 6, lane = tid & 63;
    int ql = lane & 31, h = lane >> 5;
    const u16* qb = q + (((size_t)bh * 1024) + s0 + wave * 32 + ql) * 64;
    bf16x8 qf[4];
#pragma unroll
    for (int kb = 0; kb < 4; kb++)
        qf[kb] = *(const bf16x8*)(qb + kb * 16 + h * 8);
    const u16* Kb = Kt + (size_t)bh * T * 64;
    const u16* Vb = Vt + (size_t)bh * 64 * T;

#define STAGEK(t0, b)                                                                    \
    _Pragma("unroll")                                                                    \
    for (int i = 0; i < 4; i++) {                                                        \
        int rw = (wave * 4 + i) * 8 + (lane >> 3);                                       \
        int sc = (((lane & 7) ^ (lane >> 3) ^ (wave * 4 + i)) & 7) << 3;                 \
        __builtin_amdgcn_global_load_lds(                                                \
            (const __attribute__((address_space(1))) void*)(Kb + (size_t)((t0) + rw) * 64 + sc), \
            (__attribute__((address_space(3))) void*)(&Ks[b][0][0] + (wave * 4 + i) * 512), \
            16, 0, 0);                                                                   \
    }

    STAGEK(tbeg, 0);
    f32x16 oacc[2] = {};
    float lrun = 0.0f;
    int buf = 0;

    for (int t0 = tbeg; t0 < tend; t0 += 64) {
        __syncthreads();                 // drains K-stage(buf); prior reads of buf^1 done
        if (t0 + 64 < tend) { STAGEK(t0 + 64, buf ^ 1); }   // in flight during compute
        uint4 vreg[8];
#pragma unroll
        for (int ts = 0; ts < 4; ts++)
#pragma unroll
            for (int db = 0; db < 2; db++)
                vreg[ts * 2 + db] = *(const uint4*)(Vb + (size_t)(db * 32 + ql) * T + t0 + ts * 16 + 8 * h);
        f32x16 sa[2] = {};
        __builtin_amdgcn_s_setprio(1);
#pragma unroll
        for (int tb = 0; tb < 2; tb++) {
#pragma unroll
            for (int kb = 0; kb < 4; kb++) {
                int rsw = (((ql & 7) ^ (tb * 4 + (ql >> 3))) & 7) << 3;
                bf16x8 kf = *(const bf16x8*)(&Ks[buf][tb * 32 + ql][(kb * 16 + 8 * h) ^ rsw]);
                sa[tb] = __builtin_amdgcn_mfma_f32_32x32x16_bf16(kf, qf[kb], sa[tb], 0, 0, 0);
            }
        }
        __builtin_amdgcn_s_setprio(0);
        float ps = 0.0f;
#pragma unroll
        for (int tb = 0; tb < 2; tb++) {
#pragma unroll
            for (int g = 0; g < 4; g++) {
                float p0 = __builtin_amdgcn_exp2f(sa[tb][4 * g + 0] - M2);
                float p1 = __builtin_amdgcn_exp2f(sa[tb][4 * g + 1] - M2);
                float p2 = __builtin_amdgcn_exp2f(sa[tb][4 * g + 2] - M2);
                float p3 = __builtin_amdgcn_exp2f(sa[tb][4 * g + 3] - M2);
                ps += (p0 + p1) + (p2 + p3);
                uint2 ww;
                ww.x = (unsigned)f2b(p0) | ((unsigned)f2b(p1) << 16);
                ww.y = (unsigned)f2b(p2) | ((unsigned)f2b(p3) << 16);
                *(uint2*)(&Ps[wave][ql][tb * 32 + 8 * g + 4 * h]) = ww;
            }
        }
        lrun += ps;
        asm volatile("s_waitcnt lgkmcnt(0)" ::: "memory");
        __builtin_amdgcn_sched_barrier(0);
        __builtin_amdgcn_s_setprio(1);
#pragma unroll
        for (int ts = 0; ts < 4; ts++) {
            bf16x8 pf = *(const bf16x8*)(&Ps[wave][ql][ts * 16 + 8 * h]);
#pragma unroll
            for (int db = 0; db < 2; db++)
                oacc[db] = __builtin_amdgcn_mfma_f32_32x32x16_bf16(
                    pf, as_bf(vreg[ts * 2 + db]), oacc[db], 0, 0, 0);
        }
        __builtin_amdgcn_s_setprio(0);
        buf ^= 1;
    }
#undef STAGEK
    float lsum = lrun + __shfl_xor(lrun, 32);
    size_t rowbase = (size_t)(chunk * 32 + bh) * 1024;
#pragma unroll
    for (int r = 0; r < 16; r++) {
        int q2 = (r & 3) + 8 * (r >> 2) + 4 * h;
        float linv = 1.0f / __shfl(lsum, q2);
        int s = s0 + wave * 32 + q2;
#pragma unroll
        for (int db = 0; db < 2; db++)
            Opart[(rowbase + s) * 64 + db * 32 + ql] = f2b(oacc[db][r] * linv);
    }
    if (lane < 32) {
        int s = s0 + wave * 32 + lane;
        mlbuf[rowbase + s] = 0.0f;            // fixed shift: m == 0 for both chunks
        mlbuf[65536 + rowbase + s] = lsum;
    }
}

// ---------------- combine the two T-chunks ----------------
__global__ __launch_bounds__(256) void attn_combine(
    const u16* __restrict__ Opart, const float* __restrict__ mlbuf,
    u16* __restrict__ aout)
{
    int idx = blockIdx.x * 256 + threadIdx.x;   // 262144 total
    int row = idx >> 3;                         // bh*1024 + s
    int d0 = (idx & 7) << 3;
    float m0 = mlbuf[row],         m1 = mlbuf[32768 + row];
    float l0 = mlbuf[65536 + row], l1 = mlbuf[65536 + 32768 + row];
    float m = fmaxf(m0, m1);
    float w0 = l0 * __expf(m0 - m);
    float w1 = l1 * __expf(m1 - m);
    float inv = 1.0f / (w0 + w1);
    w0 *= inv; w1 *= inv;
    bf16x8 o0 = *(const bf16x8*)(Opart + (size_t)row * 64 + d0);
    bf16x8 o1 = *(const bf16x8*)(Opart + 2097152 + (size_t)row * 64 + d0);
    u16x8 o;
#pragma unroll
    for (int j = 0; j < 8; j++)
        o[j] = f2b(w0 * b2f(o0[j]) + w1 * b2f(o1[j]));
    int bh = row >> 10, s = row & 1023;
    int b = bh >> 4, h = bh & 15;
    *(u16x8*)(aout + ((size_t)b * 1024 + s) * 1024 + h * 64 + d0) = o;
}

extern "C" void kernel_launch(void* const* d_in, const int* in_sizes, int n_in,
                              void* d_out, int out_size, void* d_ws, size_t ws_size,
                              hipStream_t stream)
{
    const float* x      = (const float*)d_in[0];
    const float* kin    = (const float*)d_in[1];
    const float* vin    = (const float*)d_in[2];
    const float* ln1w   = (const float*)d_in[3];
    const float* ln1b   = (const float*)d_in[4];
    const float* ln2w   = (const float*)d_in[5];
    const float* ln2b   = (const float*)d_in[6];
    const float* w_attn = (const float*)d_in[7];
    const float* b_attn = (const float*)d_in[8];
    const float* w_proj = (const float*)d_in[9];
    const float* b_proj = (const float*)d_in[10];
    const float* w_fc   = (const float*)d_in[11];
    const float* b_fc   = (const float*)d_in[12];
    const float* w_fc2  = (const float*)d_in[13];
    const float* b_fc2  = (const float*)d_in[14];

    float* xout = (float*)d_out;
    float* newk = xout + 2097152;
    float* newv = newk + 2097152;

    char* w = (char*)d_ws;
    u16* wT_attn = (u16*)w;  w += 6291456;   // [3072,1024]
    u16* wT_proj = (u16*)w;  w += 2097152;   // [1024,1024]
    u16* wT_fc   = (u16*)w;  w += 8388608;   // [4096,1024]
    u16* wT_fc2  = (u16*)w;  w += 8388608;   // [1024,4096]
    u16* h1a     = (u16*)w;  w += 4194304;   // ln1 out, later attn out [B,S,D]
    u16* qh2     = (u16*)w;  w += 4194304;   // q [B,H,S,DH], later ln2 out
    u16* Kt      = (u16*)w;  w += 8388608;   // [B,H,2048,64]
    u16* Vt      = (u16*)w;  w += 8388608;   // [B,H,64,2048]
    u16* g       = (u16*)w;                  // 16 MB: attn partials, then fc out [2048,4096]
    u16* Opart   = g;                        // [2][32][1024][64] bf16 = 8.39 MB
    float* mlbuf = (float*)(g + 4194304);    // 131072 floats = 0.5 MB

    dim3 blk(256);
    transpose_cvt<<<dim3(48, 16, 1), blk, 0, stream>>>(w_attn, wT_attn, 1024, 3072, 0, 1024);
    transpose_cvt<<<dim3(16, 16, 1), blk, 0, stream>>>(w_proj, wT_proj, 1024, 1024, 0, 1024);
    transpose_cvt<<<dim3(64, 16, 1), blk, 0, stream>>>(w_fc,   wT_fc,   1024, 4096, 0, 1024);
    transpose_cvt<<<dim3(16, 64, 1), blk, 0, stream>>>(w_fc2,  wT_fc2,  4096, 1024, 0, 4096);
    transpose_cvt<<<dim3(16, 1, 32), blk, 0, stream>>>(kin, Kt, 64, 1024, 131072, 64);
    transpose_cvt<<<dim3(1, 16, 32), blk, 0, stream>>>(vin, Vt, 1024, 64, 131072, 2048);

    ln_kernel<<<2048, blk, 0, stream>>>(x, ln1w, ln1b, h1a);

    // qkv: tile 128x64 -> grid 48x16 = 768 blocks (3/CU)
    gemm_bt<0><<<dim3(48, 16, 1), blk, 0, stream>>>(h1a, wT_attn, b_attn, 2048, 3072, 1024, 1024,
        nullptr, nullptr, nullptr, qh2, newk, newv, Kt, Vt);

    attn_kernel<<<dim3(1024), dim3(128), 0, stream>>>(qh2, Kt, Vt, Opart, mlbuf);
    attn_combine<<<1024, blk, 0, stream>>>(Opart, mlbuf, h1a);

    // proj: grid 16x16 = 256 blocks (1/CU)
    gemm_bt<1><<<dim3(16, 16, 1), blk, 0, stream>>>(h1a, wT_proj, b_proj, 2048, 1024, 1024, 1024,
        xout, x, nullptr, nullptr, nullptr, nullptr, nullptr, nullptr);

    ln_kernel<<<2048, blk, 0, stream>>>(xout, ln2w, ln2b, qh2);

    // fc1: grid 64x16 = 1024 blocks (4/CU cap; 3/CU with 48KB LDS)
    gemm_bt<2><<<dim3(64, 16, 1), blk, 0, stream>>>(qh2, wT_fc, b_fc, 2048, 4096, 1024, 1024,
        nullptr, nullptr, g, nullptr, nullptr, nullptr, nullptr, nullptr);

    // fc2 split-K x4: grid 16x16x4 = 1024 blocks, atomicAdd into xout (holds residual)
    gemm_bt<3><<<dim3(16, 16, 4), blk, 0, stream>>>(g, wT_fc2, b_fc2, 2048, 1024, 4096, 1024,
        xout, nullptr, nullptr, nullptr, nullptr, nullptr, nullptr, nullptr);
}